// Round 13
// baseline (192.206 us; speedup 1.0000x reference)
//
#include <hip/hip_runtime.h>
#include <stdint.h>

typedef unsigned short u16;
typedef unsigned int u32;
typedef __attribute__((ext_vector_type(8))) short short8;   // 8 bf16 = 4 VGPR
typedef __attribute__((ext_vector_type(4))) short s16x4;
typedef __attribute__((ext_vector_type(4))) float f32x4;
typedef __attribute__((ext_vector_type(16))) float f32x16;
typedef __attribute__((ext_vector_type(4))) int int4v;

#define MFMA16(a,b,c) __builtin_amdgcn_mfma_f32_16x16x32_bf16(a,b,c,0,0,0)
#define MFMA32(a,b,c) __builtin_amdgcn_mfma_f32_32x32x16_bf16(a,b,c,0,0,0)

constexpr int B_ = 4, C_ = 512, N_ = 4096, D_ = 64;  // D_ = CQK = C/8

static __device__ __forceinline__ u16 f2bf(float f) {
    uint32_t u = __builtin_bit_cast(uint32_t, f);
    uint32_t r = (u + 0x7FFFu + ((u >> 16) & 1u)) >> 16;   // RNE
    return (u16)r;
}

// ---------------- prep: Wcat bf16 [640][512] + biascat; Wq/bq pre-scaled by log2(e) ----
__global__ void prep_w(const float* Wq, const float* bq, const float* Wk, const float* bk,
                       const float* Wv, const float* bv, u16* Wcat, float* biascat) {
    const float LOG2E = 1.44269504088896340736f;
    int idx = blockIdx.x * 256 + threadIdx.x;
    if (idx < 640 * 512) {
        int row = idx >> 9, col = idx & 511;
        float w;
        if (row < 64)        w = Wq[row * 512 + col] * LOG2E;
        else if (row < 128)  w = Wk[(row - 64) * 512 + col];
        else                 w = Wv[(row - 128) * 512 + col];
        Wcat[idx] = f2bf(w);
    }
    if (idx < 640) {
        float bb;
        if (idx < 64)        bb = bq[idx] * LOG2E;
        else if (idx < 128)  bb = bk[idx - 64];
        else                 bb = bv[idx - 128];
        biascat[idx] = bb;
    }
}

// ---------------- transpose x [B][C][N] f32 -> xT [B][N][C] bf16 ----------------
__global__ void transpose_x(const float* __restrict__ x, u16* __restrict__ xT) {
    __shared__ float tile[32][33];
    int n0 = blockIdx.x * 32, c0 = blockIdx.y * 32, b = blockIdx.z;
    int tx = threadIdx.x & 31, ty = threadIdx.x >> 5;       // ty 0..7
    const float* xb = x + (size_t)b * C_ * N_;
#pragma unroll
    for (int r = 0; r < 4; r++) {
        int c = ty * 4 + r;
        tile[c][tx] = xb[(size_t)(c0 + c) * N_ + n0 + tx];
    }
    __syncthreads();
    u16* xTb = xT + (size_t)b * N_ * C_;
#pragma unroll
    for (int r = 0; r < 4; r++) {
        int n = ty * 4 + r;
        xTb[(size_t)(n0 + n) * C_ + c0 + tx] = f2bf(tile[tx][n]);
    }
}

// ---------------- projection GEMM: Y[640][4096] = Wcat x X_b^T, per batch --------
__global__ __launch_bounds__(256) void proj_gemm(const u16* __restrict__ Wcat,
                                                 const float* __restrict__ biascat,
                                                 const u16* __restrict__ xT,
                                                 u16* __restrict__ qT, u16* __restrict__ kT,
                                                 u16* __restrict__ v) {
    int b = blockIdx.z;
    int m0 = blockIdx.y * 64;
    int wave = threadIdx.x >> 6, lane = threadIdx.x & 63;
    int n0 = blockIdx.x * 256 + wave * 64;
    int lr = lane & 15, lc = lane >> 4;
    const u16* xTb = xT + (size_t)b * N_ * C_;

    f32x4 acc[4][4] = {};
    short8 aF[4], bF[4], aFn[4], bFn[4];
#pragma unroll
    for (int ma = 0; ma < 4; ma++)
        aF[ma] = *reinterpret_cast<const short8*>(&Wcat[(size_t)(m0 + ma * 16 + lr) * 512 + lc * 8]);
#pragma unroll
    for (int na = 0; na < 4; na++)
        bF[na] = *reinterpret_cast<const short8*>(&xTb[(size_t)(n0 + na * 16 + lr) * 512 + lc * 8]);

    for (int k0 = 0; k0 < 512; k0 += 32) {
        if (k0 < 480) {
            int kn = k0 + 32;
#pragma unroll
            for (int ma = 0; ma < 4; ma++)
                aFn[ma] = *reinterpret_cast<const short8*>(&Wcat[(size_t)(m0 + ma * 16 + lr) * 512 + kn + lc * 8]);
#pragma unroll
            for (int na = 0; na < 4; na++)
                bFn[na] = *reinterpret_cast<const short8*>(&xTb[(size_t)(n0 + na * 16 + lr) * 512 + kn + lc * 8]);
        }
#pragma unroll
        for (int ma = 0; ma < 4; ma++)
#pragma unroll
            for (int na = 0; na < 4; na++)
                acc[ma][na] = MFMA16(aF[ma], bF[na], acc[ma][na]);
#pragma unroll
        for (int t = 0; t < 4; t++) { aF[t] = aFn[t]; bF[t] = bFn[t]; }
    }
#pragma unroll
    for (int ma = 0; ma < 4; ma++) {
#pragma unroll
        for (int r = 0; r < 4; r++) {
            int m = m0 + ma * 16 + lc * 4 + r;
            float bias = biascat[m];
#pragma unroll
            for (int na = 0; na < 4; na++) {
                int n = n0 + na * 16 + lr;
                u16 hv = f2bf(acc[ma][na][r] + bias);
                if (m < 64)
                    qT[((size_t)b * N_ + n) * D_ + m] = hv;
                else if (m < 128)
                    kT[((size_t)b * N_ + n) * D_ + (m - 64)] = hv;
                else
                    v[((size_t)b * C_ + (m - 128)) * (size_t)N_ + n] = hv;
            }
        }
    }
}

// ---------------- fused attention: wave-independent S, in-register P, permuted V ----------------
// 512 blocks x 256 thr (4 waves), 2 blocks/CU (decoupled barriers). Wave owns 32 i x 128 c,
// computes its own S for all j (QK^T dup x4 across c-slices); P never leaves the wave.
// KEY (R13): V is staged into LDS with a per-16 j-permutation (jj = j with bits2<->3
// swapped), chosen so the PV A-operand is DIRECTLY cvt_pk(p[0..7]) / cvt_pk(p[8..15]) --
// no shfl_xor / cndmask lane exchange (PV sums over j; permuting j in both P and V is
// exact). K (8KB) & V (16KB) 64-j tiles double-buffered in XOR-swizzled LDS; one barrier
// per jt guards staging only. mfma32 layouts as verified in R12 (bit-identical output).
__global__ __launch_bounds__(256, 2) void attn(const u16* __restrict__ qT, const u16* __restrict__ kT,
                                               const u16* __restrict__ v, const float* __restrict__ x,
                                               const float* __restrict__ gamma_p, float* __restrict__ out) {
    int blk = blockIdx.x;               // [0,512)
    int xcd = blk & 7, rest = blk >> 3; // rest in [0,64)
    int b = xcd >> 1;
    int cs = (xcd & 1) + 2 * (rest & 1);    // c-slice 0..3
    int itile = rest >> 1;                   // 0..31 (CU pair: same cs, itiles 16 apart)
    int c0 = cs * 128;
    int ib0 = itile * 128;

    int tid = threadIdx.x;
    int wv = tid >> 6, lane = tid & 63;
    int li = lane & 31, hi = lane >> 5;

    __shared__ char smem[49152];
    char* Kb0 = smem;                    // [64 j][128B], swz ^((j&7)<<4)
    char* Kb1 = smem + 8192;
    char* Vb0 = smem + 16384;            // [128 c][128B], swz ^((c&7)<<4), j-permuted
    char* Vb1 = smem + 32768;

    const u16* qTb = qT + (size_t)b * N_ * D_;
    const u16* kTb = kT + (size_t)b * N_ * D_;
    const u16* vb  = v  + (size_t)b * C_ * N_;

    // Q fragments (B-operand of mfma32: row=li=i, k=hi*8+e), 4 d-chunks of 16
    short8 qf[4];
#pragma unroll
    for (int dc = 0; dc < 4; dc++)
        qf[dc] = *reinterpret_cast<const short8*>(
            &qTb[(size_t)(ib0 + wv * 32 + li) * D_ + dc * 16 + hi * 8]);

    f32x16 acc[4] = {};                 // [ct]: O[i=crow(r,hi)][c = ct*32+li]
    float lsum = 0.f;

    // ---- staging roles (256 threads) ----
    // K: 2 chunks/thread: rows tid>>3 and +32, col octet (tid&7)*8
    int krow0 = tid >> 3, kcol = (tid & 7) * 8;
    int koff0 = krow0 * 128 + ((kcol * 2) ^ ((krow0 & 7) << 4));
    int koff1 = (krow0 + 32) * 128 + ((kcol * 2) ^ ((krow0 & 7) << 4));  // (+32)&7 == &7
    // V: 4 chunks/thread: rows tid>>3 + 32n, j-octet a=(tid&7); stored PERMUTED:
    //   j=8a..8a+3 -> jj_lo = 16*(a>>1) + (a&1)*4 ; j=8a+4..8a+7 -> jj_lo+8
    int vc0 = tid >> 3, va = tid & 7;
    int jj_lo = 16 * (va >> 1) + (va & 1) * 4;
    int vswz = (vc0 & 7) << 4;                         // (+32n)&7 == &7
    int voff_lo = vc0 * 128 + ((jj_lo * 2) ^ vswz);
    int voff_hi = vc0 * 128 + ((jj_lo * 2 + 16) ^ vswz);

    // ---- prologue: stage tile 0 ----
    {
        short8 k0 = *reinterpret_cast<const short8*>(&kTb[(size_t)krow0 * D_ + kcol]);
        short8 k1 = *reinterpret_cast<const short8*>(&kTb[(size_t)(krow0 + 32) * D_ + kcol]);
        *reinterpret_cast<short8*>(Kb0 + koff0) = k0;
        *reinterpret_cast<short8*>(Kb0 + koff1) = k1;
#pragma unroll
        for (int n = 0; n < 4; n++) {
            short8 vv = *reinterpret_cast<const short8*>(&vb[(size_t)(c0 + vc0 + 32 * n) * N_ + va * 8]);
            s16x4 lo = __builtin_shufflevector(vv, vv, 0, 1, 2, 3);
            s16x4 hi4 = __builtin_shufflevector(vv, vv, 4, 5, 6, 7);
            *reinterpret_cast<s16x4*>(Vb0 + n * 4096 + voff_lo) = lo;
            *reinterpret_cast<s16x4*>(Vb0 + n * 4096 + voff_hi) = hi4;
        }
    }
    __syncthreads();

    int swz = (li & 7) << 4;
    for (int jt = 0; jt < 64; jt++) {
        char* Kc = (jt & 1) ? Kb1 : Kb0;
        char* Vc = (jt & 1) ? Vb1 : Vb0;
        char* Kn = (jt & 1) ? Kb0 : Kb1;
        char* Vn = (jt & 1) ? Vb0 : Vb1;

        // ---- issue next tile's staging loads (written to LDS after compute) ----
        short8 kst0, kst1, vstg[4];
        if (jt < 63) {
            int j1 = (jt + 1) * 64;
            kst0 = *reinterpret_cast<const short8*>(&kTb[(size_t)(j1 + krow0) * D_ + kcol]);
            kst1 = *reinterpret_cast<const short8*>(&kTb[(size_t)(j1 + krow0 + 32) * D_ + kcol]);
#pragma unroll
            for (int n = 0; n < 4; n++)
                vstg[n] = *reinterpret_cast<const short8*>(
                    &vb[(size_t)(c0 + vc0 + 32 * n) * N_ + j1 + va * 8]);
        }

        // ---- S + exp + pack for both 32-j chunks (wave-local, no exchange) ----
        short8 PA[2][2];
#pragma unroll
        for (int jc = 0; jc < 2; jc++) {
            int jr = (jc * 32 + li) * 128;
            short8 kf0 = *reinterpret_cast<const short8*>(Kc + jr + ((0  + hi * 16) ^ swz));
            short8 kf1 = *reinterpret_cast<const short8*>(Kc + jr + ((32 + hi * 16) ^ swz));
            short8 kf2 = *reinterpret_cast<const short8*>(Kc + jr + ((64 + hi * 16) ^ swz));
            short8 kf3 = *reinterpret_cast<const short8*>(Kc + jr + ((96 + hi * 16) ^ swz));
            f32x16 S = {};
            S = MFMA32(kf0, qf[0], S);
            S = MFMA32(kf1, qf[1], S);
            S = MFMA32(kf2, qf[2], S);
            S = MFMA32(kf3, qf[3], S);
            float p[16];
#pragma unroll
            for (int r = 0; r < 16; r++) p[r] = __builtin_amdgcn_exp2f(S[r]);
            lsum += (((p[0]+p[1])+(p[2]+p[3]))+((p[4]+p[5])+(p[6]+p[7])))
                  + (((p[8]+p[9])+(p[10]+p[11]))+((p[12]+p[13])+(p[14]+p[15])));
            u32 w[8];
#pragma unroll
            for (int k = 0; k < 8; k++)
                asm("v_cvt_pk_bf16_f32 %0, %1, %2" : "=v"(w[k]) : "v"(p[2 * k]), "v"(p[2 * k + 1]));
            int4v a0 = { (int)w[0], (int)w[1], (int)w[2], (int)w[3] };
            int4v a1 = { (int)w[4], (int)w[5], (int)w[6], (int)w[7] };
            PA[jc][0] = __builtin_bit_cast(short8, a0);   // A[k=hi*8+e] = P[j = jc*32 + j16(k)]
            PA[jc][1] = __builtin_bit_cast(short8, a1);   // j16 matches permuted V storage
        }

        // ---- PV: 16 mfma32, V read from permuted LDS (contents match PA's j order) ----
#pragma unroll
        for (int jc = 0; jc < 2; jc++)
#pragma unroll
            for (int ct = 0; ct < 4; ct++) {
                const char* vrow = Vc + (ct * 32 + li) * 128;
                short8 vf0 = *reinterpret_cast<const short8*>(vrow + ((jc * 64 + hi * 16) ^ swz));
                short8 vf1 = *reinterpret_cast<const short8*>(vrow + ((jc * 64 + 32 + hi * 16) ^ swz));
                acc[ct] = MFMA32(PA[jc][0], vf0, acc[ct]);
                acc[ct] = MFMA32(PA[jc][1], vf1, acc[ct]);
            }

        // ---- write staged regs into the other buffer, then the only barrier ----
        if (jt < 63) {
            *reinterpret_cast<short8*>(Kn + koff0) = kst0;
            *reinterpret_cast<short8*>(Kn + koff1) = kst1;
#pragma unroll
            for (int n = 0; n < 4; n++) {
                s16x4 lo = __builtin_shufflevector(vstg[n], vstg[n], 0, 1, 2, 3);
                s16x4 hi4 = __builtin_shufflevector(vstg[n], vstg[n], 4, 5, 6, 7);
                *reinterpret_cast<s16x4*>(Vn + n * 4096 + voff_lo) = lo;
                *reinterpret_cast<s16x4*>(Vn + n * 4096 + voff_hi) = hi4;
            }
        }
        asm volatile("s_waitcnt lgkmcnt(0)" ::: "memory");
        __builtin_amdgcn_s_barrier();
    }

    // ---- finalize: row sums, normalize, transpose via per-wave LDS, residual ----
    float lfull = lsum + __shfl_xor(lsum, 32);   // full row-sum for i=li
    float g = gamma_p[0];
    float* olds = reinterpret_cast<float*>(smem + wv * 4608);   // [32 c][36] f32 per wave
    const float* xb = x + (size_t)b * C_ * N_;
    float* ob = out + (size_t)b * C_ * N_;
#pragma unroll
    for (int ct = 0; ct < 4; ct++) {
#pragma unroll
        for (int r = 0; r < 16; r++) {
            int crow = (r & 3) + 8 * (r >> 2) + 4 * hi;     // i-local
            float linv = 1.0f / __shfl(lfull, crow);
            olds[li * 36 + crow] = g * acc[ct][r] * linv;
        }
        asm volatile("s_waitcnt lgkmcnt(0)" ::: "memory");
#pragma unroll
        for (int cp = 0; cp < 4; cp++) {
            int c_l = cp * 8 + (lane >> 3);
            int i4 = (lane & 7) * 4;
            float4 o4 = *reinterpret_cast<const float4*>(&olds[c_l * 36 + i4]);
            size_t off = (size_t)(c0 + ct * 32 + c_l) * N_ + ib0 + wv * 32 + i4;
            float4 xv = *reinterpret_cast<const float4*>(&xb[off]);
            float4 ov = { o4.x + xv.x, o4.y + xv.y, o4.z + xv.z, o4.w + xv.w };
            *reinterpret_cast<float4*>(&ob[off]) = ov;
        }
        asm volatile("s_waitcnt lgkmcnt(0)" ::: "memory");
    }
}

extern "C" void kernel_launch(void* const* d_in, const int* in_sizes, int n_in,
                              void* d_out, int out_size, void* d_ws, size_t ws_size,
                              hipStream_t stream) {
    const float* x     = (const float*)d_in[0];
    const float* Wq    = (const float*)d_in[1];
    const float* bq    = (const float*)d_in[2];
    const float* Wk    = (const float*)d_in[3];
    const float* bk    = (const float*)d_in[4];
    const float* Wv    = (const float*)d_in[5];
    const float* bv    = (const float*)d_in[6];
    const float* gamma = (const float*)d_in[7];
    float* out = (float*)d_out;

    char* ws = (char*)d_ws;
    // layout (bytes): xT 16MB | Wcat 640KB | biascat 4KB | qT 2MB | kT 2MB | v 16MB
    u16*   xT      = (u16*)ws;
    u16*   Wcat    = (u16*)(ws + (size_t)16777216);
    float* biascat = (float*)(ws + (size_t)16777216 + 655360);
    u16*   qT      = (u16*)(ws + (size_t)16777216 + 655360 + 4096);
    u16*   kT      = qT + (size_t)B_ * N_ * D_;
    u16*   v       = kT + (size_t)B_ * N_ * D_;

    prep_w<<<1280, 256, 0, stream>>>(Wq, bq, Wk, bk, Wv, bv, Wcat, biascat);
    transpose_x<<<dim3(N_ / 32, C_ / 32, B_), 256, 0, stream>>>(x, xT);
    proj_gemm<<<dim3(N_ / 256, 640 / 64, B_), 256, 0, stream>>>(Wcat, biascat, xT, qT, kT, v);
    attn<<<512, 256, 0, stream>>>(qT, kT, v, x, gamma, out);
}